// Round 4
// baseline (588.271 us; speedup 1.0000x reference)
//
#include <hip/hip_runtime.h>
#include <hip/hip_fp16.h>

typedef _Float16 h8v __attribute__((ext_vector_type(8)));  // arithmetic type
typedef __fp16   hf8 __attribute__((ext_vector_type(8)));  // builtin ABI type
typedef float    f4v __attribute__((ext_vector_type(4)));
typedef unsigned int u32;

#define DEV __device__ __forceinline__

constexpr int NB  = 256;   // batch
constexpr int GG  = 4096;  // global_info_dim
constexpr int D1  = 512;   // 2H
constexpr int HD  = 256;   // H

DEV u32 pk2(float a, float b) {
    auto r = __builtin_amdgcn_cvt_pkrtz(a, b);   // __fp16 x2
    return __builtin_bit_cast(u32, r);
}
DEV f4v mfma16(uint4 a, h8v b, f4v c) {
    return __builtin_amdgcn_mfma_f32_16x16x32_f16(
        __builtin_bit_cast(hf8, a), __builtin_bit_cast(hf8, b), c, 0, 0, 0);
}
DEV float silu(float x) { return __fdividef(x, 1.f + __expf(-x)); }

// ---------- kernel 1: LN stats -> xn fp16; W2 -> fp16 TRANSPOSED ------------
// w2t[n][h][k] (k-contiguous) so gemm2 A-frags load directly from global.
__global__ __launch_bounds__(256) void k_prep(
        const float* __restrict__ ns, const float* __restrict__ pools,
        const float* __restrict__ W2,
        _Float16* __restrict__ xnh, _Float16* __restrict__ w2t)
{
    const int t = threadIdx.x;
    const int bid = blockIdx.x;
    __shared__ float tl[64][68];
    if (bid < NB) {
        f4v v[4];
        float s = 0.f, s2 = 0.f;
        #pragma unroll
        for (int p = 0; p < 4; ++p) {
            int i4 = t + 256*p;
            const float* src = (i4 < 512) ? (ns + (size_t)bid*2048 + i4*4)
                                          : (pools + (size_t)bid*2048 + (i4-512)*4);
            v[p] = *(const f4v*)src;
            #pragma unroll
            for (int j = 0; j < 4; ++j) { s += v[p][j]; s2 += v[p][j]*v[p][j]; }
        }
        #pragma unroll
        for (int o = 32; o > 0; o >>= 1) { s += __shfl_down(s, o); s2 += __shfl_down(s2, o); }
        __shared__ float red[8];
        if ((t & 63) == 0) { red[t>>6] = s; red[4 + (t>>6)] = s2; }
        __syncthreads();
        float ts   = red[0]+red[1]+red[2]+red[3];
        float ts2  = red[4]+red[5]+red[6]+red[7];
        float mu   = ts  * (1.f/4096.f);
        float var  = ts2 * (1.f/4096.f) - mu*mu;
        float rstd = rsqrtf(var + 1e-5f);
        #pragma unroll
        for (int p = 0; p < 4; ++p) {
            int i4 = t + 256*p;
            u32 w0 = pk2((v[p][0]-mu)*rstd, (v[p][1]-mu)*rstd);
            u32 w1 = pk2((v[p][2]-mu)*rstd, (v[p][3]-mu)*rstd);
            *(uint2*)(xnh + (size_t)bid*GG + i4*4) = make_uint2(w0, w1);
        }
    } else {
        // 1024 blocks: transpose-cast one 64k x 64h tile of W2
        const int q  = bid - NB;
        const int n  = q >> 5;
        const int kq = (q & 31) >> 2, hq = q & 3;
        const int kr = t >> 4, hc = 4*(t & 15);
        #pragma unroll
        for (int p = 0; p < 4; ++p) {
            f4v v = *(const f4v*)(W2 + ((size_t)n*D1 + kq*64 + kr + 16*p)*HD + hq*64 + hc);
            *(f4v*)&tl[kr + 16*p][hc] = v;
        }
        __syncthreads();
        const int h = t & 63, kc0 = 16*(t >> 6);
        float v[16];
        #pragma unroll
        for (int j = 0; j < 16; ++j) v[j] = tl[kc0 + j][h];
        uint4 o0, o1;
        o0.x = pk2(v[0],v[1]);   o0.y = pk2(v[2],v[3]);
        o0.z = pk2(v[4],v[5]);   o0.w = pk2(v[6],v[7]);
        o1.x = pk2(v[8],v[9]);   o1.y = pk2(v[10],v[11]);
        o1.z = pk2(v[12],v[13]); o1.w = pk2(v[14],v[15]);
        _Float16* dst = w2t + ((size_t)n*HD + hq*64 + h)*D1 + kq*64 + kc0;
        *(uint4*)dst       = o0;
        *(uint4*)(dst + 8) = o1;
    }
}

// ---------- kernel 2: hp16 = silu(xn @ (lnw*W1) + lnb@W1 + b1) --------------
// grid (8 dt, 32 n), 512 thr = 8 waves. Full K=4096, BK=64. Operand-swapped
// MFMA: A = W1'-frags (LDS), B = xn-frags (global, L2-hot) -> C rows = d,
// cols = b -> lane holds 4 consecutive d -> fused bias+SiLU+fp16 pack.
__global__ __launch_bounds__(512, 2) void k_gemm1(
        const _Float16* __restrict__ xnh, const float* __restrict__ lnw,
        const float* __restrict__ lnb, const float* __restrict__ W1,
        const float* __restrict__ b1, _Float16* __restrict__ hp16)
{
    const int dt = blockIdx.x;
    const int n  = blockIdx.y;
    const int t  = threadIdx.x;
    const int l  = t & 63;
    const int w  = t >> 6;

    __shared__ u32 lb[64*32];      // 8 KB fp16 tile, swizzled
    __shared__ float redb[512];
    __shared__ float biasv[64];

    const float* W1p = W1 + (size_t)n*GG*D1 + dt*64;
    const float* lwp = lnw + n*GG;
    const float* lbp = lnb + n*GG;

    // staging: thread owns column d = l, g-rows g0..g0+7 (wave-uniform g0)
    const int d = l, g0 = 8*w;
    const int wp = d*32 + (((w ^ (d & 7)) & 7) << 2);   // b128 write, bank-clean

    // A-frag read offsets: row = d, dwords qq = kc*4 + (l>>4)
    int rp[2][4];
    #pragma unroll
    for (int kc = 0; kc < 2; ++kc)
        #pragma unroll
        for (int mi = 0; mi < 4; ++mi) {
            int row = mi*16 + (l & 15);
            rp[kc][mi] = row*32 + ((((kc*4 + (l >> 4)) ^ (row & 7)) & 7) << 2);
        }

    // B-frag (xn) row pointers: wave w covers b = 32w .. 32w+31
    const _Float16* xrow[2];
    #pragma unroll
    for (int ni = 0; ni < 2; ++ni)
        xrow[ni] = xnh + (size_t)(32*w + ni*16 + (l & 15))*GG + 8*(l >> 4);

    float st[8];
    f4v lwa, lwb, lba, lbb;
    #pragma unroll
    for (int j = 0; j < 8; ++j) st[j] = W1p[(size_t)(g0 + j)*D1 + d];
    lwa = *(const f4v*)(lwp + g0);     lwb = *(const f4v*)(lwp + g0 + 4);
    lba = *(const f4v*)(lbp + g0);     lbb = *(const f4v*)(lbp + g0 + 4);

    f4v acc[4][2];
    #pragma unroll
    for (int mi = 0; mi < 4; ++mi)
        #pragma unroll
        for (int ni = 0; ni < 2; ++ni)
            #pragma unroll
            for (int r = 0; r < 4; ++r) acc[mi][ni][r] = 0.f;
    float bacc = 0.f;

    for (int kt = 0; kt < 64; ++kt) {
        __syncthreads();                       // A: frag reads of prev tile done
        // bias partial + lnw-scale + pack + one b128 LDS write
        uint4 pw;
        bacc += lba[0]*st[0] + lba[1]*st[1] + lba[2]*st[2] + lba[3]*st[3]
              + lbb[0]*st[4] + lbb[1]*st[5] + lbb[2]*st[6] + lbb[3]*st[7];
        pw.x = pk2(st[0]*lwa[0], st[1]*lwa[1]);
        pw.y = pk2(st[2]*lwa[2], st[3]*lwa[3]);
        pw.z = pk2(st[4]*lwb[0], st[5]*lwb[1]);
        pw.w = pk2(st[6]*lwb[2], st[7]*lwb[3]);
        *(uint4*)&lb[wp] = pw;
        __syncthreads();                       // B: tile visible
        // xn B-frags FIRST (oldest outstanding -> MFMA's vmcnt keeps st alive)
        h8v xa[2][2];
        #pragma unroll
        for (int kc = 0; kc < 2; ++kc)
            #pragma unroll
            for (int ni = 0; ni < 2; ++ni)
                xa[kc][ni] = *(const h8v*)(xrow[ni] + kt*64 + kc*32);
        // W1 prefetch for kt+1 (stays in flight through the MFMAs)
        if (kt + 1 < 64) {
            const float* src = W1p + (size_t)(kt + 1)*64*D1;
            #pragma unroll
            for (int j = 0; j < 8; ++j) st[j] = src[(size_t)(g0 + j)*D1 + d];
            lwa = *(const f4v*)(lwp + (kt+1)*64 + g0);
            lwb = *(const f4v*)(lwp + (kt+1)*64 + g0 + 4);
            lba = *(const f4v*)(lbp + (kt+1)*64 + g0);
            lbb = *(const f4v*)(lbp + (kt+1)*64 + g0 + 4);
        }
        #pragma unroll
        for (int kc = 0; kc < 2; ++kc) {
            uint4 fa[4];
            #pragma unroll
            for (int mi = 0; mi < 4; ++mi) fa[mi] = *(const uint4*)&lb[rp[kc][mi]];
            #pragma unroll
            for (int mi = 0; mi < 4; ++mi)
                #pragma unroll
                for (int ni = 0; ni < 2; ++ni)
                    acc[mi][ni] = mfma16(fa[mi], xa[kc][ni], acc[mi][ni]);
        }
    }

    // bias = sum over waves of bacc + b1
    __syncthreads();
    redb[t] = bacc;
    __syncthreads();
    if (t < 64) {
        float s = b1[n*D1 + dt*64 + t];
        #pragma unroll
        for (int j = 0; j < 8; ++j) s += redb[j*64 + t];
        biasv[t] = s;
    }
    __syncthreads();

    // fused epilogue: +bias, SiLU, fp16, store (lane holds 4 consecutive d)
    #pragma unroll
    for (int mi = 0; mi < 4; ++mi) {
        f4v bi = *(const f4v*)&biasv[mi*16 + (l >> 4)*4];
        #pragma unroll
        for (int ni = 0; ni < 2; ++ni) {
            f4v x = acc[mi][ni] + bi;
            uint2 o = make_uint2(pk2(silu(x[0]), silu(x[1])),
                                 pk2(silu(x[2]), silu(x[3])));
            int b  = 32*w + ni*16 + (l & 15);
            int dd = dt*64 + mi*16 + (l >> 4)*4;
            *(uint2*)(hp16 + ((size_t)n*NB + b)*D1 + dd) = o;
        }
    }
}

// ---------- kernel 3: out = hp16 @ w2t^T + b2 + qe + pools ------------------
// grid (32 n, 8 bq), 512 thr = 8 waves (4 h-quads x 2 b-halves). LDS-free:
// both operands load directly as fragments (w2t k-contiguous, hp16 k-contig).
// Same-n blocks share blockIdx%8 -> same XCD -> w2t L2-served.
__global__ __launch_bounds__(512, 2) void k_gemm2(
        const _Float16* __restrict__ hp16, const _Float16* __restrict__ w2t,
        const float* __restrict__ b2, const float* __restrict__ qe,
        const float* __restrict__ pools, float* __restrict__ out)
{
    const int n  = blockIdx.x;
    const int bq = blockIdx.y;
    const int t  = threadIdx.x;
    const int l  = t & 63;
    const int hw = (t >> 6) >> 1;        // 0..3
    const int bw = (t >> 6) & 1;         // 0..1

    const int b = bq*32 + bw*16 + (l & 15);
    const _Float16* hrow = hp16 + ((size_t)n*NB + b)*D1 + 8*(l >> 4);
    const _Float16* wbase = w2t + (size_t)n*HD*D1 + 8*(l >> 4);

    f4v acc[4];
    #pragma unroll
    for (int mi = 0; mi < 4; ++mi)
        #pragma unroll
        for (int r = 0; r < 4; ++r) acc[mi][r] = 0.f;

    #pragma unroll 4
    for (int ks = 0; ks < 16; ++ks) {
        h8v hb = *(const h8v*)(hrow + ks*32);
        uint4 wa[4];
        #pragma unroll
        for (int mi = 0; mi < 4; ++mi) {
            int h = hw*64 + mi*16 + (l & 15);
            wa[mi] = *(const uint4*)(wbase + (size_t)h*D1 + ks*32);
        }
        #pragma unroll
        for (int mi = 0; mi < 4; ++mi)
            acc[mi] = mfma16(wa[mi], hb, acc[mi]);
    }

    const int s = n >> 2;
    #pragma unroll
    for (int mi = 0; mi < 4; ++mi) {
        int h0 = hw*64 + mi*16 + (l >> 4)*4;
        f4v ad = *(const f4v*)(b2 + n*HD + h0);
        f4v qv = *(const f4v*)(qe + n*HD + h0);
        f4v pv = *(const f4v*)(pools + (size_t)b*2048 + s*HD + h0);
        f4v v = acc[mi] + ad + qv + pv;
        *(f4v*)(out + ((size_t)b*32 + n)*HD + h0) = v;
    }
}

extern "C" void kernel_launch(void* const* d_in, const int* in_sizes, int n_in,
                              void* d_out, int out_size, void* d_ws, size_t ws_size,
                              hipStream_t stream) {
    const float* ns   = (const float*)d_in[0];
    const float* pool = (const float*)d_in[1];
    const float* lnw  = (const float*)d_in[2];
    const float* lnb  = (const float*)d_in[3];
    const float* W1   = (const float*)d_in[4];
    const float* b1   = (const float*)d_in[5];
    const float* W2   = (const float*)d_in[6];
    const float* b2   = (const float*)d_in[7];
    const float* qe   = (const float*)d_in[8];
    float* out = (float*)d_out;

    char* ws = (char*)d_ws;
    _Float16* xnh  = (_Float16*)ws;                     // 2 MB
    _Float16* w2t  = (_Float16*)(ws + (2u  << 20));     // 8 MB
    _Float16* hp16 = (_Float16*)(ws + (10u << 20));     // 8 MB

    hipLaunchKernelGGL(k_prep,  dim3(NB + 1024), dim3(256), 0, stream,
                       ns, pool, W2, xnh, w2t);
    // gemm1 launched TWICE on purpose: Delta(dur) vs the single-launch round
    // isolates gemm1's true duration (top-5 rocprof slots are harness fills).
    hipLaunchKernelGGL(k_gemm1, dim3(8, 32), dim3(512), 0, stream,
                       xnh, lnw, lnb, W1, b1, hp16);
    hipLaunchKernelGGL(k_gemm1, dim3(8, 32), dim3(512), 0, stream,
                       xnh, lnw, lnb, W1, b1, hp16);
    hipLaunchKernelGGL(k_gemm2, dim3(32, 8), dim3(512), 0, stream,
                       hp16, w2t, b2, qe, pool, out);
}